// Round 1
// baseline (270.756 us; speedup 1.0000x reference)
//
#include <hip/hip_runtime.h>

// Involution: out[b, g*64+c, ho, wo] = sum_{kh,kw} xp[b, g*64+c, ho+kh, wo+kw] * W[b,g,kh,kw,ho,wo]
// B=8, C=512, G=8, cpg=64, H=W=Ho=Wo=64, K=7, PAD=3. fp32.
//
// R5: latency pipelining. R4 was latency-bound (VALUBusy 19%, HBM 25%, occ 38%):
// every global load (x stage + weight taps) was consumed immediately after issue.
//   - x planes for chunk cc+1 prefetched into regs DURING compute of chunk cc
//     (~1600 VALU cycles of cover before the ds_write consumes them).
//   - weight taps double-buffered across kh (wka/wkb, compile-time selection):
//     tap row kh+1 issued before the kh FMA block; tap row 0 of the next chunk
//     issued during kh=6 so it flies across the chunk barrier.
//   - asm memory clobber at chunk-loop top stops LICM from hoisting all 49
//     chunk-invariant weight loads (the R1-R3 98-reg spill failure mode).
// Live regs ~110 (q 32 + acc 16 + wk 28 + addr/temps) < 128 cap of (256,4).

#define BB 8
#define CC 512
#define GG 8
#define CPG 64
#define HH 64
#define WW 64
#define HW (HH * WW)
#define KK 7
#define PAD 3

#define TILE_ROWS 8
#define CSPLIT 2
#define NCHUNK 4                         // channel chunks per block
#define CHPC 8                           // channels per chunk
#define LDS_ROWS (TILE_ROWS + KK - 1)    // 14
#define LDS_PITCH 72                     // x col c -> lds col c+4
#define CH_STRIDE (LDS_ROWS * LDS_PITCH) // 1008 words per channel plane
#define NQUADS (LDS_ROWS * (LDS_PITCH / 4))  // 252 quad slots per plane

__global__ __launch_bounds__(256, 4)
void involution_kernel(const float* __restrict__ x,
                       const float* __restrict__ weight,
                       float* __restrict__ out) {
    const int tid = threadIdx.x;
    const int tx = tid & 31;          // wo0 = 2*tx
    const int ty = tid >> 5;          // row within tile
    const int bx = blockIdx.x;        // 0..15
    const int tile = bx >> 1;
    const int cs = bx & 1;
    const int g = blockIdx.y;
    const int b = blockIdx.z;

    const int wo0 = tx << 1;
    const int hbase = tile * TILE_ROWS;
    const int ho = hbase + ty;

    __shared__ float xs[CHPC * CH_STRIDE];   // 32256 B

    // per-pixel weight base: taps at +t*HW, float2 covers wo0,wo0+1
    const float* wq = weight + ((size_t)(b * GG + g) * (KK * KK)) * HW
                    + ho * WW + wo0;

    // staging geometry
    const int sr = tid / 18;              // 0..13 (tid < 252)
    const int sq = tid - sr * 18;         // 0..17
    const int xrow = hbase + sr - PAD;
    const int xcol = sq * 4 - 4;          // -4..64, quad aligned
    const bool sval = (tid < NQUADS)
                   && ((unsigned)xrow < HH) && ((unsigned)xcol < WW);
    const int soff = xrow * WW + xcol;
    const int ldsoff = sr * LDS_PITCH + sq * 4;

    const size_t cbase = (size_t)(b * CC + g * CPG + cs * (NCHUNK * CHPC)) * HW;
    const float* xg = x + cbase;
    float* og = out + cbase + ho * WW + wo0;

    // ---- prologue: stage chunk 0 into regs, load kh=0 taps ----
    float4 q[CHPC];
#pragma unroll
    for (int ch = 0; ch < CHPC; ++ch) {
        float4 v = make_float4(0.f, 0.f, 0.f, 0.f);
        if (sval)
            v = *(const float4*)(xg + (size_t)ch * HW + soff);
        q[ch] = v;
    }
    float2 wka[KK], wkb[KK];
#pragma unroll
    for (int j = 0; j < KK; ++j)
        wka[j] = *(const float2*)(wq + (size_t)j * HW);

#pragma unroll 1
    for (int cc = 0; cc < NCHUNK; ++cc) {
        asm volatile("" ::: "memory");   // keep the 49 weight loads in-loop
        if (cc) __syncthreads();         // previous chunk's readers done
        if (tid < NQUADS) {
#pragma unroll
            for (int ch = 0; ch < CHPC; ++ch)
                *(float4*)(&xs[ch * CH_STRIDE + ldsoff]) = q[ch];
        }
        __syncthreads();                 // planes visible

        // ---- prefetch next chunk's x planes (hidden under compute) ----
        if (cc + 1 < NCHUNK) {
#pragma unroll
            for (int ch = 0; ch < CHPC; ++ch) {
                float4 v = make_float4(0.f, 0.f, 0.f, 0.f);
                if (sval)
                    v = *(const float4*)(xg + (size_t)((cc + 1) * CHPC + ch) * HW + soff);
                q[ch] = v;
            }
        }

        float acc0[CHPC], acc1[CHPC];
#pragma unroll
        for (int ch = 0; ch < CHPC; ++ch) { acc0[ch] = 0.f; acc1[ch] = 0.f; }

        // ---- compute: kh fully unrolled; taps double-buffered wka/wkb ----
#define KH_STEP(KH, WCUR, WNXT, NKH)                                        \
        {                                                                   \
            _Pragma("unroll")                                               \
            for (int j = 0; j < KK; ++j)                                    \
                WNXT[j] = *(const float2*)(wq + (size_t)((NKH) * KK + j) * HW); \
            _Pragma("unroll")                                               \
            for (int ch = 0; ch < CHPC; ++ch) {                             \
                const float* row = &xs[ch * CH_STRIDE + (ty + (KH)) * LDS_PITCH + wo0]; \
                const float2 p0 = *(const float2*)(row + 0);                \
                const float2 p1 = *(const float2*)(row + 2);                \
                const float2 p2 = *(const float2*)(row + 4);                \
                const float2 p3 = *(const float2*)(row + 6);                \
                const float2 p4 = *(const float2*)(row + 8);                \
                const float f1 = p0.y, f2 = p1.x, f3 = p1.y, f4 = p2.x;     \
                const float f5 = p2.y, f6 = p3.x, f7 = p3.y, f8 = p4.x;     \
                float a0 = acc0[ch], a1 = acc1[ch];                         \
                a0 = fmaf(f1, WCUR[0].x, a0);  a1 = fmaf(f2, WCUR[0].y, a1); \
                a0 = fmaf(f2, WCUR[1].x, a0);  a1 = fmaf(f3, WCUR[1].y, a1); \
                a0 = fmaf(f3, WCUR[2].x, a0);  a1 = fmaf(f4, WCUR[2].y, a1); \
                a0 = fmaf(f4, WCUR[3].x, a0);  a1 = fmaf(f5, WCUR[3].y, a1); \
                a0 = fmaf(f5, WCUR[4].x, a0);  a1 = fmaf(f6, WCUR[4].y, a1); \
                a0 = fmaf(f6, WCUR[5].x, a0);  a1 = fmaf(f7, WCUR[5].y, a1); \
                a0 = fmaf(f7, WCUR[6].x, a0);  a1 = fmaf(f8, WCUR[6].y, a1); \
                acc0[ch] = a0; acc1[ch] = a1;                               \
            }                                                               \
        }

        KH_STEP(0, wka, wkb, 1)
        KH_STEP(1, wkb, wka, 2)
        KH_STEP(2, wka, wkb, 3)
        KH_STEP(3, wkb, wka, 4)
        KH_STEP(4, wka, wkb, 5)
        KH_STEP(5, wkb, wka, 6)
        KH_STEP(6, wka, wkb, 0)   // prefetch kh=0 taps for the next chunk
#undef KH_STEP

        // rotate so next chunk's kh=0 computes from wka (compile-time parity fix)
#pragma unroll
        for (int j = 0; j < KK; ++j) wka[j] = wkb[j];

        // ---- store 8 channels x 2 pixels ----
#pragma unroll
        for (int ch = 0; ch < CHPC; ++ch) {
            *(float2*)(og + (size_t)(cc * CHPC + ch) * HW)
                = make_float2(acc0[ch], acc1[ch]);
        }
    }
}

extern "C" void kernel_launch(void* const* d_in, const int* in_sizes, int n_in,
                              void* d_out, int out_size, void* d_ws, size_t ws_size,
                              hipStream_t stream) {
    const float* x = (const float*)d_in[0];
    const float* w = (const float*)d_in[1];
    float* out = (float*)d_out;

    dim3 grid((HH / TILE_ROWS) * CSPLIT, GG, BB);   // (16, 8, 8) = 1024 blocks
    dim3 block(256);
    involution_kernel<<<grid, block, 0, stream>>>(x, w, out);
}

// Round 2
// 269.264 us; speedup vs baseline: 1.0055x; 1.0055x over previous
//
#include <hip/hip_runtime.h>

// Involution: out[b, g*64+c, ho, wo] = sum_{kh,kw} xp[b, g*64+c, ho+kh, wo+kw] * W[b,g,kh,kw,ho,wo]
// B=8, C=512, G=8, cpg=64, H=W=Ho=Wo=64, K=7, PAD=3. fp32.
//
// R6: R5's pipeline + amdgpu_waves_per_eu(4,4).
// R5 post-mortem: __launch_bounds__(256,4) only sets MIN waves/EU; the
// allocator still targeted 8 waves/EU (64-VGPR budget) and spilled the
// pipeline state to scratch (FETCH 124->379 MB, WRITE 77->125 MB, dur 170us).
// Occupancy is LDS-limited to ~3-4 blocks/CU regardless, so the 8-wave target
// buys nothing. waves_per_eu(4,4) pins the budget at 128 VGPR; peak live
// state ~115 (q 32 + wka/wkb 28 + acc 16 + addr/temps ~35) fits without
// spill, letting the latency pipeline actually run:
//   - x planes for chunk cc+1 prefetched into regs DURING compute of chunk cc.
//   - weight taps double-buffered across kh (compile-time wka/wkb selection);
//     next chunk's kh=0 taps issued during kh=6, fly across the barrier.
//   - asm memory clobber keeps the 49 chunk-invariant weight loads in-loop
//     (hoisting them = 98 live regs = guaranteed spill).

#define BB 8
#define CC 512
#define GG 8
#define CPG 64
#define HH 64
#define WW 64
#define HW (HH * WW)
#define KK 7
#define PAD 3

#define TILE_ROWS 8
#define CSPLIT 2
#define NCHUNK 4                         // channel chunks per block
#define CHPC 8                           // channels per chunk
#define LDS_ROWS (TILE_ROWS + KK - 1)    // 14
#define LDS_PITCH 72                     // x col c -> lds col c+4
#define CH_STRIDE (LDS_ROWS * LDS_PITCH) // 1008 words per channel plane
#define NQUADS (LDS_ROWS * (LDS_PITCH / 4))  // 252 quad slots per plane

__global__ __launch_bounds__(256)
__attribute__((amdgpu_waves_per_eu(4, 4)))
void involution_kernel(const float* __restrict__ x,
                       const float* __restrict__ weight,
                       float* __restrict__ out) {
    const int tid = threadIdx.x;
    const int tx = tid & 31;          // wo0 = 2*tx
    const int ty = tid >> 5;          // row within tile
    const int bx = blockIdx.x;        // 0..15
    const int tile = bx >> 1;
    const int cs = bx & 1;
    const int g = blockIdx.y;
    const int b = blockIdx.z;

    const int wo0 = tx << 1;
    const int hbase = tile * TILE_ROWS;
    const int ho = hbase + ty;

    __shared__ float xs[CHPC * CH_STRIDE];   // 32256 B

    // per-pixel weight base: taps at +t*HW, float2 covers wo0,wo0+1
    const float* wq = weight + ((size_t)(b * GG + g) * (KK * KK)) * HW
                    + ho * WW + wo0;

    // staging geometry
    const int sr = tid / 18;              // 0..13 (tid < 252)
    const int sq = tid - sr * 18;         // 0..17
    const int xrow = hbase + sr - PAD;
    const int xcol = sq * 4 - 4;          // -4..64, quad aligned
    const bool sval = (tid < NQUADS)
                   && ((unsigned)xrow < HH) && ((unsigned)xcol < WW);
    const int soff = xrow * WW + xcol;
    const int ldsoff = sr * LDS_PITCH + sq * 4;

    const size_t cbase = (size_t)(b * CC + g * CPG + cs * (NCHUNK * CHPC)) * HW;
    const float* xg = x + cbase;
    float* og = out + cbase + ho * WW + wo0;

    // ---- prologue: stage chunk 0 into regs, load kh=0 taps ----
    float4 q[CHPC];
#pragma unroll
    for (int ch = 0; ch < CHPC; ++ch) {
        float4 v = make_float4(0.f, 0.f, 0.f, 0.f);
        if (sval)
            v = *(const float4*)(xg + (size_t)ch * HW + soff);
        q[ch] = v;
    }
    float2 wka[KK], wkb[KK];
#pragma unroll
    for (int j = 0; j < KK; ++j)
        wka[j] = *(const float2*)(wq + (size_t)j * HW);

#pragma unroll 1
    for (int cc = 0; cc < NCHUNK; ++cc) {
        asm volatile("" ::: "memory");   // keep the 49 weight loads in-loop
        if (cc) __syncthreads();         // previous chunk's readers done
        if (tid < NQUADS) {
#pragma unroll
            for (int ch = 0; ch < CHPC; ++ch)
                *(float4*)(&xs[ch * CH_STRIDE + ldsoff]) = q[ch];
        }
        __syncthreads();                 // planes visible

        // ---- prefetch next chunk's x planes (hidden under compute) ----
        if (cc + 1 < NCHUNK) {
#pragma unroll
            for (int ch = 0; ch < CHPC; ++ch) {
                float4 v = make_float4(0.f, 0.f, 0.f, 0.f);
                if (sval)
                    v = *(const float4*)(xg + (size_t)((cc + 1) * CHPC + ch) * HW + soff);
                q[ch] = v;
            }
        }

        float acc0[CHPC], acc1[CHPC];
#pragma unroll
        for (int ch = 0; ch < CHPC; ++ch) { acc0[ch] = 0.f; acc1[ch] = 0.f; }

        // ---- compute: kh fully unrolled; taps double-buffered wka/wkb ----
#define KH_STEP(KH, WCUR, WNXT, NKH)                                        \
        {                                                                   \
            _Pragma("unroll")                                               \
            for (int j = 0; j < KK; ++j)                                    \
                WNXT[j] = *(const float2*)(wq + (size_t)((NKH) * KK + j) * HW); \
            _Pragma("unroll")                                               \
            for (int ch = 0; ch < CHPC; ++ch) {                             \
                const float* row = &xs[ch * CH_STRIDE + (ty + (KH)) * LDS_PITCH + wo0]; \
                const float2 p0 = *(const float2*)(row + 0);                \
                const float2 p1 = *(const float2*)(row + 2);                \
                const float2 p2 = *(const float2*)(row + 4);                \
                const float2 p3 = *(const float2*)(row + 6);                \
                const float2 p4 = *(const float2*)(row + 8);                \
                const float f1 = p0.y, f2 = p1.x, f3 = p1.y, f4 = p2.x;     \
                const float f5 = p2.y, f6 = p3.x, f7 = p3.y, f8 = p4.x;     \
                float a0 = acc0[ch], a1 = acc1[ch];                         \
                a0 = fmaf(f1, WCUR[0].x, a0);  a1 = fmaf(f2, WCUR[0].y, a1); \
                a0 = fmaf(f2, WCUR[1].x, a0);  a1 = fmaf(f3, WCUR[1].y, a1); \
                a0 = fmaf(f3, WCUR[2].x, a0);  a1 = fmaf(f4, WCUR[2].y, a1); \
                a0 = fmaf(f4, WCUR[3].x, a0);  a1 = fmaf(f5, WCUR[3].y, a1); \
                a0 = fmaf(f5, WCUR[4].x, a0);  a1 = fmaf(f6, WCUR[4].y, a1); \
                a0 = fmaf(f6, WCUR[5].x, a0);  a1 = fmaf(f7, WCUR[5].y, a1); \
                a0 = fmaf(f7, WCUR[6].x, a0);  a1 = fmaf(f8, WCUR[6].y, a1); \
                acc0[ch] = a0; acc1[ch] = a1;                               \
            }                                                               \
        }

        KH_STEP(0, wka, wkb, 1)
        KH_STEP(1, wkb, wka, 2)
        KH_STEP(2, wka, wkb, 3)
        KH_STEP(3, wkb, wka, 4)
        KH_STEP(4, wka, wkb, 5)
        KH_STEP(5, wkb, wka, 6)
        KH_STEP(6, wka, wkb, 0)   // prefetch kh=0 taps for the next chunk
#undef KH_STEP

        // rotate so next chunk's kh=0 computes from wka (compile-time parity fix)
#pragma unroll
        for (int j = 0; j < KK; ++j) wka[j] = wkb[j];

        // ---- store 8 channels x 2 pixels ----
#pragma unroll
        for (int ch = 0; ch < CHPC; ++ch) {
            *(float2*)(og + (size_t)(cc * CHPC + ch) * HW)
                = make_float2(acc0[ch], acc1[ch]);
        }
    }
}

extern "C" void kernel_launch(void* const* d_in, const int* in_sizes, int n_in,
                              void* d_out, int out_size, void* d_ws, size_t ws_size,
                              hipStream_t stream) {
    const float* x = (const float*)d_in[0];
    const float* w = (const float*)d_in[1];
    float* out = (float*)d_out;

    dim3 grid((HH / TILE_ROWS) * CSPLIT, GG, BB);   // (16, 8, 8) = 1024 blocks
    dim3 block(256);
    involution_kernel<<<grid, block, 0, stream>>>(x, w, out);
}